// Round 8
// baseline (194.728 us; speedup 1.0000x reference)
//
#include <hip/hip_runtime.h>
#include <hip/hip_bf16.h>

#define B_SZ 8192
#define D_SZ 1024   // elements; == bytes in fp8

typedef __attribute__((ext_vector_type(4))) float floatx4;
typedef __attribute__((ext_vector_type(8))) int   int8v;
typedef __attribute__((ext_vector_type(4))) int   int4v;

__device__ __forceinline__ void glds16(const void* g, void* l) {
    __builtin_amdgcn_global_load_lds(
        (const __attribute__((address_space(1))) void*)g,
        (__attribute__((address_space(3))) void*)l, 16, 0, 0);
}

// One wave per row (rows 0..8191 = img, 8192..16383 = txt). 4 rows/block.
// Also zero-inits the output accumulator (stream-ordered before GEMM atomics).
__global__ __launch_bounds__(256) void norm_cast_fp8(
    const float* __restrict__ img, const float* __restrict__ txt,
    unsigned char* __restrict__ imgQ, unsigned char* __restrict__ txtQ,
    float* __restrict__ out)
{
    if (blockIdx.x == 0 && threadIdx.x == 0) *out = 0.0f;

    const int lane = threadIdx.x & 63;
    int w = blockIdx.x * 4 + (threadIdx.x >> 6);
    const float* src; unsigned char* dst;
    if (w < B_SZ) { src = img + (size_t)w * D_SZ; dst = imgQ + (size_t)w * D_SZ; }
    else { w -= B_SZ; src = txt + (size_t)w * D_SZ; dst = txtQ + (size_t)w * D_SZ; }

    float4 v[4];
    float ss = 0.0f;
    #pragma unroll
    for (int i = 0; i < 4; ++i) {
        v[i] = ((const float4*)src)[lane + 64 * i];
        ss += v[i].x*v[i].x + v[i].y*v[i].y + v[i].z*v[i].z + v[i].w*v[i].w;
    }
    #pragma unroll
    for (int off = 1; off < 64; off <<= 1) ss += __shfl_xor(ss, off, 64);
    const float scale = 1.0f / fmaxf(sqrtf(ss), 1e-12f);

    #pragma unroll
    for (int i = 0; i < 4; ++i) {
        int packed = 0;
        packed = __builtin_amdgcn_cvt_pk_fp8_f32(v[i].x * scale, v[i].y * scale, packed, false);
        packed = __builtin_amdgcn_cvt_pk_fp8_f32(v[i].z * scale, v[i].w * scale, packed, true);
        ((int*)dst)[lane + 64 * i] = packed;
    }
}

// Fused MX-fp8 GEMM (A @ B^T) + SigLIP loss. Block tile 256x256, 512 threads
// = 8 waves in 2(m)x4(n); wave tile 128x64 (8mt x 4nt of 16x16x128
// scaled-MFMA, scales = 1.0). BK=128 -> 8 K-iters. Full double-buffer of
// both tiles (128.5 KB LDS, 1 block/CU), ONE barrier per K-iter; the kk+1
// DMA has the whole iteration to land.
//
// R8 = R7 + register diet (R7 spilled ~8 regs/thread: WRITE_SIZE 16 MB).
// 8 waves/block forces 2 waves/SIMD -> hard 256-reg combined budget with
// acc[8][4] = 128 AGPRs. Staging addresses are now four persistent 32-bit
// offsets (+ scalar k0) instead of per-iter 64-bit recompute; fragment LDS
// addresses are two persistent per-lane bases with buf/mt folded into the
// ds_read offset immediate (buf*32768 + mt*1024 + {0,16} < 64 KB).
//
// LDS geometry per buffer: lo/hi 64-B-row arrays (R2's layout); granule at
// logical g stored at physical p = g ^ ((row>>1)&3); swizzle applied on the
// GLOBAL side of global_load_lds (LDS side stays wave-uniform base+lane*16).
__global__ __launch_bounds__(512, 2) void siglip_gemm_loss_fp8(
    const unsigned char* __restrict__ A,   // imgQ [B,D] e4m3
    const unsigned char* __restrict__ Bt,  // txtQ [B,D] e4m3
    const float* __restrict__ tp, const float* __restrict__ bp,
    float* __restrict__ out)
{
    // [buf][lo/hi][256*64]
    __shared__ __align__(16) unsigned char As[2][2][256 * 64]; // 64 KB
    __shared__ __align__(16) unsigned char Bs[2][2][256 * 64]; // 64 KB

    const int tid  = threadIdx.x;
    const int lane = tid & 63;
    const int wave = tid >> 6;
    const int wm = wave & 1;        // 0..1 -> m-offset wm*128
    const int wn = wave >> 1;       // 0..3 -> n-offset wn*64
    const int bi = blockIdx.x * 256;
    const int bj = blockIdx.y * 256;
    const int quad = lane >> 4;     // 0..3 -> 32-byte K-chunk
    const int l16  = lane & 15;

    floatx4 acc[8][4];
    #pragma unroll
    for (int i = 0; i < 8; ++i)
        #pragma unroll
        for (int j = 0; j < 4; ++j)
            acc[i][j] = (floatx4){0.f, 0.f, 0.f, 0.f};

    // --- staging offsets (u32; buffers are 8 MB so this always fits) ---
    // slot s -> row = s>>2, phys p = s&3, global granule g = p ^ ((row>>1)&3)
    const int s0 = tid, s1 = tid + 512;
    const int r0 = s0 >> 2, g0 = (s0 & 3) ^ ((r0 >> 1) & 3);
    const int r1 = s1 >> 2, g1 = (s1 & 3) ^ ((r1 >> 1) & 3);
    const unsigned offA0 = (unsigned)(bi + r0) * D_SZ + (unsigned)g0 * 16;
    const unsigned offA1 = (unsigned)(bi + r1) * D_SZ + (unsigned)g1 * 16;
    const unsigned offB0 = (unsigned)(bj + r0) * D_SZ + (unsigned)g0 * 16;
    const unsigned offB1 = (unsigned)(bj + r1) * D_SZ + (unsigned)g1 * 16;

    // --- fragment read geometry (proven R2/R4): array = quad>>1, granule
    // pair (quad&1)*2 ^ sw (sw=(l16>>1)&3), physical positions p0, p0^1. ---
    const int sw   = (l16 >> 1) & 3;
    const int hsel = quad >> 1;
    const int p0   = ((quad & 1) * 2) ^ sw;
    // per-lane LDS base addresses (buf/mt/nt folded into ds_read imm offset)
    const unsigned char* a_base = As[0][0] + hsel * 16384
                                + (wm * 128 + l16) * 64 + p0 * 16;
    const unsigned char* b_base = Bs[0][0] + hsel * 16384
                                + (wn * 64 + l16) * 64 + p0 * 16;
    // lo/hi granules differ by XOR 1 in physical position -> byte offset ^16.
    // ds_read at (addr + imm): lo at +0, hi at +(p0^1 - p0)*16 = +16 or -16.
    const int hi_delta = (((p0 ^ 1) - p0) * 16);   // +16 if p0 even, -16 if odd

    auto stage = [&](int k0, int buf) {
        const int d = buf * 32768;
        glds16(A  + offA0 + k0,      As[0][0] + d + s0 * 16);
        glds16(A  + offA0 + k0 + 64, As[0][1] + d + s0 * 16);
        glds16(A  + offA1 + k0,      As[0][0] + d + s1 * 16);
        glds16(A  + offA1 + k0 + 64, As[0][1] + d + s1 * 16);
        glds16(Bt + offB0 + k0,      Bs[0][0] + d + s0 * 16);
        glds16(Bt + offB0 + k0 + 64, Bs[0][1] + d + s0 * 16);
        glds16(Bt + offB1 + k0,      Bs[0][0] + d + s1 * 16);
        glds16(Bt + offB1 + k0 + 64, Bs[0][1] + d + s1 * 16);
    };

    stage(0, 0);

    for (int kk = 0; kk < D_SZ / 128; ++kk) {
        const int buf = kk & 1;
        const int bofs = buf * 32768;
        __syncthreads();   // own-DMA vmcnt drained by each wave before barrier
                           // => buf's tiles fully visible; buf^1 readers done.

        if (kk + 1 < D_SZ / 128)
            stage((kk + 1) * 128, buf ^ 1);  // lands anytime before next barrier

        int8v bfr[4];
        #pragma unroll
        for (int nt = 0; nt < 4; ++nt) {
            const unsigned char* bp_ = b_base + bofs + nt * 1024;
            int4v lo = *(const int4v*)(bp_);
            int4v hi = *(const int4v*)(bp_ + hi_delta);
            bfr[nt][0]=lo[0]; bfr[nt][1]=lo[1]; bfr[nt][2]=lo[2]; bfr[nt][3]=lo[3];
            bfr[nt][4]=hi[0]; bfr[nt][5]=hi[1]; bfr[nt][6]=hi[2]; bfr[nt][7]=hi[3];
        }

        #pragma unroll
        for (int mt = 0; mt < 8; ++mt) {
            const unsigned char* ap_ = a_base + bofs + mt * 1024;
            int4v lo = *(const int4v*)(ap_);
            int4v hi = *(const int4v*)(ap_ + hi_delta);
            int8v af;
            af[0]=lo[0]; af[1]=lo[1]; af[2]=lo[2]; af[3]=lo[3];
            af[4]=hi[0]; af[5]=hi[1]; af[6]=hi[2]; af[7]=hi[3];
            #pragma unroll
            for (int nt = 0; nt < 4; ++nt)
                acc[mt][nt] = __builtin_amdgcn_mfma_scale_f32_16x16x128_f8f6f4(
                    af, bfr[nt], acc[mt][nt],
                    0, 0,          // cbsz=fp8, blgp=fp8
                    0, 127,        // scale A: E8M0 127 = 1.0
                    0, 127);       // scale B
        }
    }

    // Epilogue: softplus(-label*logit) with hw exp/log, reduce.
    const float t    = fminf(__expf(tp[0]), 100.0f);
    const float bias = bp[0];
    float lsum = 0.0f;
    #pragma unroll
    for (int mt = 0; mt < 8; ++mt) {
        #pragma unroll
        for (int nt = 0; nt < 4; ++nt) {
            const int jj = bj + wn * 64 + nt * 16 + l16;               // C/D col
            #pragma unroll
            for (int r = 0; r < 4; ++r) {
                const int ii = bi + wm * 128 + mt * 16 + quad * 4 + r; // C/D row
                float logit = fmaf(acc[mt][nt][r], t, bias);
                float z = (ii == jj) ? logit : -logit;
                float e = __expf(-fabsf(z));
                lsum += fmaxf(-z, 0.0f) + __logf(1.0f + e);
            }
        }
    }
    #pragma unroll
    for (int off = 32; off > 0; off >>= 1) lsum += __shfl_down(lsum, off, 64);

    __shared__ float red[8];
    if (lane == 0) red[wave] = lsum;
    __syncthreads();
    if (tid == 0) {
        float s = 0.0f;
        #pragma unroll
        for (int i = 0; i < 8; ++i) s += red[i];
        atomicAdd(out, s * (1.0f / (float)B_SZ));
    }
}

extern "C" void kernel_launch(void* const* d_in, const int* in_sizes, int n_in,
                              void* d_out, int out_size, void* d_ws, size_t ws_size,
                              hipStream_t stream) {
    const float* img = (const float*)d_in[0];
    const float* txt = (const float*)d_in[1];
    const float* tp  = (const float*)d_in[2];
    const float* bp  = (const float*)d_in[3];
    float* out = (float*)d_out;

    unsigned char* imgQ = (unsigned char*)d_ws;                   // 8 MB
    unsigned char* txtQ = imgQ + (size_t)B_SZ * D_SZ;             // 8 MB

    norm_cast_fp8<<<(2 * B_SZ) / 4, 256, 0, stream>>>(img, txt, imgQ, txtQ, out);
    dim3 grid(B_SZ / 256, B_SZ / 256);
    siglip_gemm_loss_fp8<<<grid, 512, 0, stream>>>(imgQ, txtQ, tp, bp, out);
}

// Round 9
// 189.699 us; speedup vs baseline: 1.0265x; 1.0265x over previous
//
#include <hip/hip_runtime.h>
#include <hip/hip_bf16.h>

#define B_SZ 8192
#define D_SZ 1024   // elements; == bytes in fp8

typedef __attribute__((ext_vector_type(4))) float floatx4;
typedef __attribute__((ext_vector_type(8))) int   int8v;
typedef __attribute__((ext_vector_type(4))) int   int4v;

__device__ __forceinline__ void glds16(const void* g, void* l) {
    __builtin_amdgcn_global_load_lds(
        (const __attribute__((address_space(1))) void*)g,
        (__attribute__((address_space(3))) void*)l, 16, 0, 0);
}

// One wave per row (rows 0..8191 = img, 8192..16383 = txt). 4 rows/block.
// Also zero-inits the output accumulator (stream-ordered before GEMM atomics).
__global__ __launch_bounds__(256) void norm_cast_fp8(
    const float* __restrict__ img, const float* __restrict__ txt,
    unsigned char* __restrict__ imgQ, unsigned char* __restrict__ txtQ,
    float* __restrict__ out)
{
    if (blockIdx.x == 0 && threadIdx.x == 0) *out = 0.0f;

    const int lane = threadIdx.x & 63;
    int w = blockIdx.x * 4 + (threadIdx.x >> 6);
    const float* src; unsigned char* dst;
    if (w < B_SZ) { src = img + (size_t)w * D_SZ; dst = imgQ + (size_t)w * D_SZ; }
    else { w -= B_SZ; src = txt + (size_t)w * D_SZ; dst = txtQ + (size_t)w * D_SZ; }

    float4 v[4];
    float ss = 0.0f;
    #pragma unroll
    for (int i = 0; i < 4; ++i) {
        v[i] = ((const float4*)src)[lane + 64 * i];
        ss += v[i].x*v[i].x + v[i].y*v[i].y + v[i].z*v[i].z + v[i].w*v[i].w;
    }
    #pragma unroll
    for (int off = 1; off < 64; off <<= 1) ss += __shfl_xor(ss, off, 64);
    const float scale = 1.0f / fmaxf(sqrtf(ss), 1e-12f);

    #pragma unroll
    for (int i = 0; i < 4; ++i) {
        int packed = 0;
        packed = __builtin_amdgcn_cvt_pk_fp8_f32(v[i].x * scale, v[i].y * scale, packed, false);
        packed = __builtin_amdgcn_cvt_pk_fp8_f32(v[i].z * scale, v[i].w * scale, packed, true);
        ((int*)dst)[lane + 64 * i] = packed;
    }
}

// Fused MX-fp8 GEMM (A @ B^T) + SigLIP loss. 128x128 block tile, 4 waves 2x2,
// wave tile 64x64 (4x4 of 16x16x128 scaled-MFMA, scales = 1.0), 8 K-iters.
//
// Conflict-free LDS geometry (R9): lo/hi arrays of 64-B rows; staging stores
// the 16 B granule with logical index g at physical pos p = g ^ ((row>>1)&3)
// (swizzle on the GLOBAL side of global_load_lds; LDS side stays slot-
// contiguous). Fragment reads use pos = quad ^ sw — R2's measured-zero-
// conflict stream where all 4 quads hit different granule positions. This
// means lane `quad` holds global K-granules {quad, quad+4} instead of
// {2*quad, 2*quad+1}: a K-PERMUTATION, which is legal because A and B use
// the identical permutation and the MFMA dot-product is K-order invariant.
//
// As is double-buffered (32 KB) + Bs single (16 KB) = 48.5 KB -> 3 blocks/CU
// (12 waves/CU at ~144 regs). Per iter: barrier1 (DMA landed) -> bfr reads ->
// barrier2 (cheap, vmcnt already 0) -> stage kk+1 (A into buf^1, B into Bs) ->
// af reads + MFMAs from As[buf] while the DMA flies.
__global__ __launch_bounds__(256, 3) void siglip_gemm_loss_fp8(
    const unsigned char* __restrict__ A,   // imgQ [B,D] e4m3
    const unsigned char* __restrict__ Bt,  // txtQ [B,D] e4m3
    const float* __restrict__ tp, const float* __restrict__ bp,
    float* __restrict__ out)
{
    __shared__ __align__(16) unsigned char As[2 * 2 * 128 * 64]; // [buf][lo/hi] 32 KB
    __shared__ __align__(16) unsigned char Bs[2 * 128 * 64];     // [lo/hi]      16 KB

    const int tid  = threadIdx.x;
    const int lane = tid & 63;
    const int wave = tid >> 6;
    const int wm = wave & 1, wn = wave >> 1;
    const int bi = blockIdx.x * 128;
    const int bj = blockIdx.y * 128;
    const int quad = lane >> 4;   // 0..3
    const int l16  = lane & 15;

    floatx4 acc[4][4];
    #pragma unroll
    for (int i = 0; i < 4; ++i)
        #pragma unroll
        for (int j = 0; j < 4; ++j)
            acc[i][j] = (floatx4){0.f, 0.f, 0.f, 0.f};

    // staging: 512 slots per half-array; slot s -> row = s>>2, phys p = s&3,
    // global granule g = p ^ ((row>>1)&3). lo = K-bytes g*16, hi = 64+g*16.
    const int s0 = tid, s1 = tid + 256;
    const int r0 = s0 >> 2, g0 = (s0 & 3) ^ ((r0 >> 1) & 3);
    const int r1 = s1 >> 2, g1 = (s1 & 3) ^ ((r1 >> 1) & 3);
    const unsigned offA0 = (unsigned)(bi + r0) * D_SZ + (unsigned)g0 * 16;
    const unsigned offA1 = (unsigned)(bi + r1) * D_SZ + (unsigned)g1 * 16;
    const unsigned offB0 = (unsigned)(bj + r0) * D_SZ + (unsigned)g0 * 16;
    const unsigned offB1 = (unsigned)(bj + r1) * D_SZ + (unsigned)g1 * 16;

    auto stage_a = [&](int k0, int buf) {
        const int d = buf * 16384;
        glds16(A + offA0 + k0,      As + d + s0 * 16);
        glds16(A + offA0 + k0 + 64, As + d + 8192 + s0 * 16);
        glds16(A + offA1 + k0,      As + d + s1 * 16);
        glds16(A + offA1 + k0 + 64, As + d + 8192 + s1 * 16);
    };
    auto stage_b = [&](int k0) {
        glds16(Bt + offB0 + k0,      Bs + s0 * 16);
        glds16(Bt + offB0 + k0 + 64, Bs + 8192 + s0 * 16);
        glds16(Bt + offB1 + k0,      Bs + s1 * 16);
        glds16(Bt + offB1 + k0 + 64, Bs + 8192 + s1 * 16);
    };

    // fragment reads: pos = quad ^ sw (sw = (l16>>1)&3; row base is a
    // multiple of 16 so (row>>1)&3 == (l16>>1)&3). Retrieved global granule
    // = pos ^ sw = quad from each array -> lane K-chunk = {g_quad, g_quad+4}.
    const int sw  = (l16 >> 1) & 3;
    const int pos = quad ^ sw;
    const unsigned a_off = (unsigned)((wm * 64 + l16) * 64 + pos * 16);
    const unsigned b_off = (unsigned)((wn * 64 + l16) * 64 + pos * 16);

    stage_a(0, 0);
    stage_b(0);

    for (int kk = 0; kk < D_SZ / 128; ++kk) {
        const int buf = kk & 1;
        const int d = buf * 16384;
        __syncthreads();   // (1) own-DMA vmcnt drained by every wave => tiles visible

        int8v bfr[4];
        #pragma unroll
        for (int nt = 0; nt < 4; ++nt) {
            const unsigned char* bp_ = Bs + b_off + nt * 1024;
            int4v lo = *(const int4v*)(bp_);
            int4v hi = *(const int4v*)(bp_ + 8192);
            bfr[nt][0]=lo[0]; bfr[nt][1]=lo[1]; bfr[nt][2]=lo[2]; bfr[nt][3]=lo[3];
            bfr[nt][4]=hi[0]; bfr[nt][5]=hi[1]; bfr[nt][6]=hi[2]; bfr[nt][7]=hi[3];
        }
        __syncthreads();   // (2) cheap: vmcnt already 0; licenses Bs overwrite

        if (kk + 1 < D_SZ / 128) {
            stage_a((kk + 1) * 128, buf ^ 1);  // As[buf^1] readers done pre-(1)
            stage_b((kk + 1) * 128);           // Bs consumed above
        }

        #pragma unroll
        for (int mt = 0; mt < 4; ++mt) {
            const unsigned char* ap_ = As + d + a_off + mt * 1024;
            int4v lo = *(const int4v*)(ap_);
            int4v hi = *(const int4v*)(ap_ + 8192);
            int8v af;
            af[0]=lo[0]; af[1]=lo[1]; af[2]=lo[2]; af[3]=lo[3];
            af[4]=hi[0]; af[5]=hi[1]; af[6]=hi[2]; af[7]=hi[3];
            #pragma unroll
            for (int nt = 0; nt < 4; ++nt)
                acc[mt][nt] = __builtin_amdgcn_mfma_scale_f32_16x16x128_f8f6f4(
                    af, bfr[nt], acc[mt][nt],
                    0, 0,          // cbsz=fp8, blgp=fp8
                    0, 127,        // scale A: E8M0 127 = 1.0
                    0, 127);       // scale B
        }
    }

    // Epilogue: softplus(-label*logit) with hw exp/log, reduce.
    const float t    = fminf(__expf(tp[0]), 100.0f);
    const float bias = bp[0];
    float lsum = 0.0f;
    #pragma unroll
    for (int mt = 0; mt < 4; ++mt) {
        #pragma unroll
        for (int nt = 0; nt < 4; ++nt) {
            const int jj = bj + wn * 64 + nt * 16 + l16;              // C/D col
            #pragma unroll
            for (int r = 0; r < 4; ++r) {
                const int ii = bi + wm * 64 + mt * 16 + quad * 4 + r; // C/D row
                float logit = fmaf(acc[mt][nt][r], t, bias);
                float z = (ii == jj) ? logit : -logit;
                float e = __expf(-fabsf(z));
                lsum += fmaxf(-z, 0.0f) + __logf(1.0f + e);
            }
        }
    }
    #pragma unroll
    for (int off = 32; off > 0; off >>= 1) lsum += __shfl_down(lsum, off, 64);

    __shared__ float red[4];
    if (lane == 0) red[wave] = lsum;
    __syncthreads();
    if (tid == 0)
        atomicAdd(out, (red[0] + red[1] + red[2] + red[3]) * (1.0f / (float)B_SZ));
}

extern "C" void kernel_launch(void* const* d_in, const int* in_sizes, int n_in,
                              void* d_out, int out_size, void* d_ws, size_t ws_size,
                              hipStream_t stream) {
    const float* img = (const float*)d_in[0];
    const float* txt = (const float*)d_in[1];
    const float* tp  = (const float*)d_in[2];
    const float* bp  = (const float*)d_in[3];
    float* out = (float*)d_out;

    unsigned char* imgQ = (unsigned char*)d_ws;                   // 8 MB
    unsigned char* txtQ = imgQ + (size_t)B_SZ * D_SZ;             // 8 MB

    norm_cast_fp8<<<(2 * B_SZ) / 4, 256, 0, stream>>>(img, txt, imgQ, txtQ, out);
    dim3 grid(B_SZ / 128, B_SZ / 128);
    siglip_gemm_loss_fp8<<<grid, 256, 0, stream>>>(imgQ, txtQ, tp, bp, out);
}

// Round 10
// 189.490 us; speedup vs baseline: 1.0276x; 1.0011x over previous
//
#include <hip/hip_runtime.h>
#include <hip/hip_bf16.h>

#define B_SZ 8192
#define D_SZ 1024   // elements; == bytes in fp8

typedef __attribute__((ext_vector_type(4))) float floatx4;
typedef __attribute__((ext_vector_type(8))) int   int8v;
typedef __attribute__((ext_vector_type(4))) int   int4v;

__device__ __forceinline__ void glds16(const void* g, void* l) {
    __builtin_amdgcn_global_load_lds(
        (const __attribute__((address_space(1))) void*)g,
        (__attribute__((address_space(3))) void*)l, 16, 0, 0);
}

// One wave per row (rows 0..8191 = img, 8192..16383 = txt). 4 rows/block.
// Also zero-inits the output accumulator (stream-ordered before GEMM atomics).
__global__ __launch_bounds__(256) void norm_cast_fp8(
    const float* __restrict__ img, const float* __restrict__ txt,
    unsigned char* __restrict__ imgQ, unsigned char* __restrict__ txtQ,
    float* __restrict__ out)
{
    if (blockIdx.x == 0 && threadIdx.x == 0) *out = 0.0f;

    const int lane = threadIdx.x & 63;
    int w = blockIdx.x * 4 + (threadIdx.x >> 6);
    const float* src; unsigned char* dst;
    if (w < B_SZ) { src = img + (size_t)w * D_SZ; dst = imgQ + (size_t)w * D_SZ; }
    else { w -= B_SZ; src = txt + (size_t)w * D_SZ; dst = txtQ + (size_t)w * D_SZ; }

    float4 v[4];
    float ss = 0.0f;
    #pragma unroll
    for (int i = 0; i < 4; ++i) {
        v[i] = ((const float4*)src)[lane + 64 * i];
        ss += v[i].x*v[i].x + v[i].y*v[i].y + v[i].z*v[i].z + v[i].w*v[i].w;
    }
    #pragma unroll
    for (int off = 1; off < 64; off <<= 1) ss += __shfl_xor(ss, off, 64);
    const float scale = 1.0f / fmaxf(sqrtf(ss), 1e-12f);

    #pragma unroll
    for (int i = 0; i < 4; ++i) {
        int packed = 0;
        packed = __builtin_amdgcn_cvt_pk_fp8_f32(v[i].x * scale, v[i].y * scale, packed, false);
        packed = __builtin_amdgcn_cvt_pk_fp8_f32(v[i].z * scale, v[i].w * scale, packed, true);
        ((int*)dst)[lane + 64 * i] = packed;
    }
}

// Fused MX-fp8 GEMM (A @ B^T) + SigLIP loss. 128x128 block tile, 4 waves 2x2,
// wave tile 64x64 (4x4 of 16x16x128 scaled-MFMA, scales = 1.0), 8 K-iters.
//
// R10 structure: FULL double-buffer of As and Bs (64.5 KB LDS, 2 blocks/CU)
// -> ONE barrier per K-iteration. At the barrier, each wave's own staging
// DMA is drained (vmcnt(0) before s_barrier) so buf's tiles are visible, and
// all waves are past their kk-1 reads of buf^1, so kk+1's DMA into buf^1 is
// issued IMMEDIATELY after the barrier and has the whole iteration to land.
// bfr/af ds_reads and MFMAs sit in one barrier-free region for the compiler
// to interleave (no pure-LDS phase starving the MFMA pipe — R9's limiter).
//
// Conflict-free LDS geometry (validated R9: SQ_LDS_BANK_CONFLICT == 0):
// lo/hi arrays of 64-B rows; staging stores granule g at physical
// p = g ^ ((row>>1)&3) via GLOBAL-side swizzle; fragment reads use
// pos = quad ^ sw, retrieving the row-independent K-permutation
// {quad, quad+4} — legal since A and B share it (MFMA K-order invariant).
__global__ __launch_bounds__(256, 2) void siglip_gemm_loss_fp8(
    const unsigned char* __restrict__ A,   // imgQ [B,D] e4m3
    const unsigned char* __restrict__ Bt,  // txtQ [B,D] e4m3
    const float* __restrict__ tp, const float* __restrict__ bp,
    float* __restrict__ out)
{
    // [buf][lo/hi][128 rows x 64 B]
    __shared__ __align__(16) unsigned char As[2 * 2 * 128 * 64]; // 32 KB
    __shared__ __align__(16) unsigned char Bs[2 * 2 * 128 * 64]; // 32 KB

    const int tid  = threadIdx.x;
    const int lane = tid & 63;
    const int wave = tid >> 6;
    const int wm = wave & 1, wn = wave >> 1;
    const int bi = blockIdx.x * 128;
    const int bj = blockIdx.y * 128;
    const int quad = lane >> 4;   // 0..3
    const int l16  = lane & 15;

    floatx4 acc[4][4];
    #pragma unroll
    for (int i = 0; i < 4; ++i)
        #pragma unroll
        for (int j = 0; j < 4; ++j)
            acc[i][j] = (floatx4){0.f, 0.f, 0.f, 0.f};

    // staging: 512 slots per half-array; slot s -> row = s>>2, phys p = s&3,
    // global granule g = p ^ ((row>>1)&3). lo = K-bytes g*16, hi = 64+g*16.
    const int s0 = tid, s1 = tid + 256;
    const int r0 = s0 >> 2, g0 = (s0 & 3) ^ ((r0 >> 1) & 3);
    const int r1 = s1 >> 2, g1 = (s1 & 3) ^ ((r1 >> 1) & 3);
    const unsigned offA0 = (unsigned)(bi + r0) * D_SZ + (unsigned)g0 * 16;
    const unsigned offA1 = (unsigned)(bi + r1) * D_SZ + (unsigned)g1 * 16;
    const unsigned offB0 = (unsigned)(bj + r0) * D_SZ + (unsigned)g0 * 16;
    const unsigned offB1 = (unsigned)(bj + r1) * D_SZ + (unsigned)g1 * 16;

    auto stage = [&](int k0, int buf) {
        const int d = buf * 16384;
        glds16(A  + offA0 + k0,      As + d + s0 * 16);
        glds16(A  + offA0 + k0 + 64, As + d + 8192 + s0 * 16);
        glds16(A  + offA1 + k0,      As + d + s1 * 16);
        glds16(A  + offA1 + k0 + 64, As + d + 8192 + s1 * 16);
        glds16(Bt + offB0 + k0,      Bs + d + s0 * 16);
        glds16(Bt + offB0 + k0 + 64, Bs + d + 8192 + s0 * 16);
        glds16(Bt + offB1 + k0,      Bs + d + s1 * 16);
        glds16(Bt + offB1 + k0 + 64, Bs + d + 8192 + s1 * 16);
    };

    // fragment reads: pos = quad ^ sw (sw = (l16>>1)&3); retrieved global
    // granule = quad from each array -> lane K-chunk = {g_quad, g_quad+4}.
    const int sw  = (l16 >> 1) & 3;
    const int pos = quad ^ sw;
    const unsigned a_off = (unsigned)((wm * 64 + l16) * 64 + pos * 16);
    const unsigned b_off = (unsigned)((wn * 64 + l16) * 64 + pos * 16);

    stage(0, 0);

    for (int kk = 0; kk < D_SZ / 128; ++kk) {
        const int buf = kk & 1;
        const int d = buf * 16384;
        __syncthreads();   // single barrier: buf tiles visible, buf^1 free

        if (kk + 1 < D_SZ / 128)
            stage((kk + 1) * 128, buf ^ 1);   // full iteration to land

        int8v bfr[4];
        #pragma unroll
        for (int nt = 0; nt < 4; ++nt) {
            const unsigned char* bp_ = Bs + d + b_off + nt * 1024;
            int4v lo = *(const int4v*)(bp_);
            int4v hi = *(const int4v*)(bp_ + 8192);
            bfr[nt][0]=lo[0]; bfr[nt][1]=lo[1]; bfr[nt][2]=lo[2]; bfr[nt][3]=lo[3];
            bfr[nt][4]=hi[0]; bfr[nt][5]=hi[1]; bfr[nt][6]=hi[2]; bfr[nt][7]=hi[3];
        }

        #pragma unroll
        for (int mt = 0; mt < 4; ++mt) {
            const unsigned char* ap_ = As + d + a_off + mt * 1024;
            int4v lo = *(const int4v*)(ap_);
            int4v hi = *(const int4v*)(ap_ + 8192);
            int8v af;
            af[0]=lo[0]; af[1]=lo[1]; af[2]=lo[2]; af[3]=lo[3];
            af[4]=hi[0]; af[5]=hi[1]; af[6]=hi[2]; af[7]=hi[3];
            #pragma unroll
            for (int nt = 0; nt < 4; ++nt)
                acc[mt][nt] = __builtin_amdgcn_mfma_scale_f32_16x16x128_f8f6f4(
                    af, bfr[nt], acc[mt][nt],
                    0, 0,          // cbsz=fp8, blgp=fp8
                    0, 127,        // scale A: E8M0 127 = 1.0
                    0, 127);       // scale B
        }
    }

    // Epilogue: softplus(-label*logit) with hw exp/log, reduce.
    const float t    = fminf(__expf(tp[0]), 100.0f);
    const float bias = bp[0];
    float lsum = 0.0f;
    #pragma unroll
    for (int mt = 0; mt < 4; ++mt) {
        #pragma unroll
        for (int nt = 0; nt < 4; ++nt) {
            const int jj = bj + wn * 64 + nt * 16 + l16;              // C/D col
            #pragma unroll
            for (int r = 0; r < 4; ++r) {
                const int ii = bi + wm * 64 + mt * 16 + quad * 4 + r; // C/D row
                float logit = fmaf(acc[mt][nt][r], t, bias);
                float z = (ii == jj) ? logit : -logit;
                float e = __expf(-fabsf(z));
                lsum += fmaxf(-z, 0.0f) + __logf(1.0f + e);
            }
        }
    }
    #pragma unroll
    for (int off = 32; off > 0; off >>= 1) lsum += __shfl_down(lsum, off, 64);

    __shared__ float red[4];
    if (lane == 0) red[wave] = lsum;
    __syncthreads();
    if (tid == 0)
        atomicAdd(out, (red[0] + red[1] + red[2] + red[3]) * (1.0f / (float)B_SZ));
}

extern "C" void kernel_launch(void* const* d_in, const int* in_sizes, int n_in,
                              void* d_out, int out_size, void* d_ws, size_t ws_size,
                              hipStream_t stream) {
    const float* img = (const float*)d_in[0];
    const float* txt = (const float*)d_in[1];
    const float* tp  = (const float*)d_in[2];
    const float* bp  = (const float*)d_in[3];
    float* out = (float*)d_out;

    unsigned char* imgQ = (unsigned char*)d_ws;                   // 8 MB
    unsigned char* txtQ = imgQ + (size_t)B_SZ * D_SZ;             // 8 MB

    norm_cast_fp8<<<(2 * B_SZ) / 4, 256, 0, stream>>>(img, txt, imgQ, txtQ, out);
    dim3 grid(B_SZ / 128, B_SZ / 128);
    siglip_gemm_loss_fp8<<<grid, 256, 0, stream>>>(imgQ, txtQ, tp, bp, out);
}